// Round 2
// baseline (595.491 us; speedup 1.0000x reference)
//
#include <hip/hip_runtime.h>
#include <cmath>

// Problem constants
#define BB 16384
#define DD 256
#define UU 256
#define TT 32
#define MM 64

// ws layout (float offsets)
#define WS_ALPHA 0
#define WS_BETA  16384
#define WS_HS1   32768
#define WS_HS2   33024
#define WS_M1    33280
#define WS_M2    33536
#define WS_V1    33792
#define WS_V2    34816
#define WS_WC    35840
// Wc: 512 x 1280 floats; total ws use = (35840 + 655360)*4 B ~= 2.64 MB

__device__ __forceinline__ float hsig(float x) {
    return fminf(1.0f, fmaxf(0.0f, fmaf(0.2f, x, 0.5f)));
}

// K0: build combined weight Wc[512][1280].
// cols 0..1023  : rows 0..255 = W, rows 256..511 = U   (gates i,f,c,o)
// cols 1024..1279: rows 0..255 = W_f (W cols 256..511), rows 256..511 = Un_f
__global__ void k_build_wc(const float* __restrict__ W, const float* __restrict__ Uw,
                           const float* __restrict__ Un, float* __restrict__ Wc) {
    int idx = blockIdx.x * 256 + threadIdx.x;   // float4 id, total 512*1280/4 = 163840
    int k  = idx / 320;
    int c4 = (idx - k * 320) * 4;
    const float* src;
    if (c4 < 1024) {
        src = (k < 256) ? (W + k * 1024 + c4) : (Uw + (k - 256) * 1024 + c4);
    } else {
        int cc = c4 - 768;   // favg block -> source cols 256..511
        src = (k < 256) ? (W + k * 1024 + cc) : (Un + (k - 256) * 1024 + cc);
    }
    float4 v = *(const float4*)src;
    *(float4*)(Wc + k * 1280 + c4) = v;
}

// K1a: hs1 = sum_b h_tm1[b,:], hs2 = sum_b h_tm2[b,:]
__global__ void k_colsum(const float* __restrict__ h1, const float* __restrict__ h2,
                         float* __restrict__ hs1, float* __restrict__ hs2) {
    int u = threadIdx.x;
    int r0 = blockIdx.x * 64;
    float s1 = 0.f, s2 = 0.f;
    for (int r = 0; r < 64; r++) {
        s1 += h1[(r0 + r) * UU + u];
        s2 += h2[(r0 + r) * UU + u];
    }
    atomicAdd(hs1 + u, s1);
    atomicAdd(hs2 + u, s2);
}

// K1b: per-batch alpha/beta. One 64-lane wave per b.
__global__ void k_coef(const int* __restrict__ neighbors, const int* __restrict__ mapping,
                       const int* __restrict__ revmap, const int* __restrict__ timep,
                       float* __restrict__ alpha, float* __restrict__ beta) {
    int lane = threadIdx.x & 63;
    int wid  = threadIdx.x >> 6;
    int b = blockIdx.x * 4 + wid;
    int t = timep[0];
    int p = revmap[b * TT + t];
    int ng = neighbors[(b * TT + p) * MM + lane];
    int mp = mapping[b * MM + lane];
    int cnt = ng;
    int cp  = (mp < t) ? ng : 0;
    #pragma unroll
    for (int off = 32; off > 0; off >>= 1) {
        cnt += __shfl_xor(cnt, off);
        cp  += __shfl_xor(cp, off);
    }
    if (lane == 0) {
        float a = 0.f, be = 0.f;
        if (cnt > 0) {
            float inv = 1.0f / (float)cnt;
            a  = (float)cp * inv;
            be = (float)(cnt - cp) * inv;
        }
        alpha[b] = a;
        beta[b]  = be;
    }
}

// K2: v1 = hs1 @ Un (1024), v2 = hs2 @ Un
__global__ void k_vmat(const float* __restrict__ Un, const float* __restrict__ hs1,
                       const float* __restrict__ hs2, float* __restrict__ v1,
                       float* __restrict__ v2) {
    __shared__ float sh1[256], sh2[256];
    sh1[threadIdx.x] = hs1[threadIdx.x];
    sh2[threadIdx.x] = hs2[threadIdx.x];
    __syncthreads();
    int j = blockIdx.x * 256 + threadIdx.x;
    float a1 = 0.f, a2 = 0.f;
    for (int k = 0; k < 256; k++) {
        float w = Un[k * 1024 + j];
        a1 = fmaf(sh1[k], w, a1);
        a2 = fmaf(sh2[k], w, a2);
    }
    v1[j] = a1;
    v2[j] = a2;
}

// K3: main fused GEMM. Block tile: 128 rows x 32 units x 5 gates. 256 threads,
// microtile 8 rows x (2 units x 5 gates). KT=32, register-prefetch pipelined.
#define BM 128
#define KT 32
#define NU 32

#define LOAD_TILE(K0) { \
    const float* srcA = ((K0) < 256) ? (inputs + (K0)) : (h1 + ((K0) - 256)); \
    _Pragma("unroll") \
    for (int it = 0; it < 4; it++) \
        pa[it] = *(const float4*)(srcA + (m0 + a_m[it]) * 256 + kvA * 4); \
    _Pragma("unroll") \
    for (int it = 0; it < 5; it++) \
        pb[it] = *(const float4*)(Wc + ((K0) + b_k[it]) * 1280 + b_g[it] * 256 + u0 + b_uv[it] * 4); \
}

__global__ __launch_bounds__(256, 2) void k_gemm(
    const float* __restrict__ inputs, const float* __restrict__ h1,
    const float* __restrict__ c1p, const float* __restrict__ c2p,
    const float* __restrict__ Wc, const float* __restrict__ bias,
    const float* __restrict__ alpha, const float* __restrict__ beta,
    const float* __restrict__ v1, const float* __restrict__ v2,
    float* __restrict__ m1, float* __restrict__ m2,
    float* __restrict__ out_h, float* __restrict__ out_mem)
{
    __shared__ float As[KT][132];      // [k][m], pad 132; b128 reads broadcast conflict-free
    __shared__ float Bs[KT][5][36];    // [k][gate][u], pad 36; b64 reads conflict-free

    int tid = threadIdx.x;
    int m0 = blockIdx.y * BM;
    int u0 = blockIdx.x * NU;
    int tr = tid >> 4;    // 0..15 row group
    int tc = tid & 15;    // 0..15 unit-pair group

    // staging-index precompute (all compile-time-ish, live in regs)
    int a_m[4];
    #pragma unroll
    for (int it = 0; it < 4; it++) a_m[it] = it * 32 + (tid >> 3);
    const int kvA = tid & 7;
    int b_k[5], b_g[5], b_uv[5];
    #pragma unroll
    for (int it = 0; it < 5; it++) {
        int idx = it * 256 + tid;
        b_k[it] = idx / 40;
        int rem = idx - b_k[it] * 40;
        b_g[it] = rem >> 3;
        b_uv[it] = rem & 7;
    }

    float acc[8][10];
    #pragma unroll
    for (int i = 0; i < 8; i++)
        #pragma unroll
        for (int j = 0; j < 10; j++) acc[i][j] = 0.f;

    float4 pa[4], pb[5];
    LOAD_TILE(0);

    for (int k0 = 0; k0 < 512; k0 += KT) {
        __syncthreads();                 // previous compute done reading LDS
        #pragma unroll
        for (int it = 0; it < 4; it++) {
            As[kvA * 4 + 0][a_m[it]] = pa[it].x;
            As[kvA * 4 + 1][a_m[it]] = pa[it].y;
            As[kvA * 4 + 2][a_m[it]] = pa[it].z;
            As[kvA * 4 + 3][a_m[it]] = pa[it].w;
        }
        #pragma unroll
        for (int it = 0; it < 5; it++)
            *(float4*)&Bs[b_k[it]][b_g[it]][b_uv[it] * 4] = pb[it];
        __syncthreads();

        if (k0 + KT < 512) LOAD_TILE(k0 + KT);   // prefetch next tile; latency hides under compute

        #pragma unroll
        for (int kk = 0; kk < KT; kk++) {
            float4 a0 = *(const float4*)&As[kk][tr * 8];
            float4 a1 = *(const float4*)&As[kk][tr * 8 + 4];
            float av[8] = {a0.x, a0.y, a0.z, a0.w, a1.x, a1.y, a1.z, a1.w};
            #pragma unroll
            for (int g = 0; g < 5; g++) {
                float2 bv = *(const float2*)&Bs[kk][g][tc * 2];
                #pragma unroll
                for (int i = 0; i < 8; i++) {
                    acc[i][g * 2 + 0] = fmaf(av[i], bv.x, acc[i][g * 2 + 0]);
                    acc[i][g * 2 + 1] = fmaf(av[i], bv.y, acc[i][g * 2 + 1]);
                }
            }
        }
    }

    // Epilogue: gates + partial memory + o (temp in out_h) + m1/m2 partial reduce
    int ub = u0 + tc * 2;
    const float2 bi  = *(const float2*)(bias + ub);
    const float2 bf  = *(const float2*)(bias + 256 + ub);
    const float2 bc  = *(const float2*)(bias + 512 + ub);
    const float2 bo  = *(const float2*)(bias + 768 + ub);
    const float2 v1i = *(const float2*)(v1 + ub);
    const float2 v1c = *(const float2*)(v1 + 512 + ub);
    const float2 v1o = *(const float2*)(v1 + 768 + ub);
    const float2 v2i = *(const float2*)(v2 + ub);
    const float2 v2c = *(const float2*)(v2 + 512 + ub);
    const float2 v2o = *(const float2*)(v2 + 768 + ub);

    float pm1_0 = 0.f, pm1_1 = 0.f, pm2_0 = 0.f, pm2_1 = 0.f;

    #pragma unroll
    for (int i = 0; i < 8; i++) {
        int b = m0 + tr * 8 + i;
        float al = alpha[b];
        float be = beta[b];
        float2 c1v = *(const float2*)(c1p + b * UU + ub);
        float2 c2v = *(const float2*)(c2p + b * UU + ub);
        float2 om, oh;
        {
            float zi  = acc[i][0] + bi.x + al * v1i.x + be * v2i.x;
            float zf  = acc[i][2] + bf.x;
            float zc  = acc[i][4] + bc.x + al * v1c.x + be * v2c.x;
            float zo  = acc[i][6] + bo.x + al * v1o.x + be * v2o.x;
            float zfa = acc[i][8] + bf.x;
            float ig = hsig(zi), fg = hsig(zf), og = hsig(zo), fa = hsig(zfa);
            float cg = tanhf(zc);
            om.x = fg * c1v.x + ig * cg;
            oh.x = og;
            pm1_0 += fa * c1v.x;
            pm2_0 += fa * c2v.x;
        }
        {
            float zi  = acc[i][1] + bi.y + al * v1i.y + be * v2i.y;
            float zf  = acc[i][3] + bf.y;
            float zc  = acc[i][5] + bc.y + al * v1c.y + be * v2c.y;
            float zo  = acc[i][7] + bo.y + al * v1o.y + be * v2o.y;
            float zfa = acc[i][9] + bf.y;
            float ig = hsig(zi), fg = hsig(zf), og = hsig(zo), fa = hsig(zfa);
            float cg = tanhf(zc);
            om.y = fg * c1v.y + ig * cg;
            oh.y = og;
            pm1_1 += fa * c1v.y;
            pm2_1 += fa * c2v.y;
        }
        *(float2*)(out_mem + b * UU + ub) = om;
        *(float2*)(out_h  + b * UU + ub) = oh;
    }

    // block-level reduce of m1/m2 partials over the 16 row groups, then one atomic per unit
    __syncthreads();
    float* red = &As[0][0];   // reuse LDS: need 2*16*36 = 1152 floats
    red[(0 * 16 + tr) * 36 + tc * 2]     = pm1_0;
    red[(0 * 16 + tr) * 36 + tc * 2 + 1] = pm1_1;
    red[(1 * 16 + tr) * 36 + tc * 2]     = pm2_0;
    red[(1 * 16 + tr) * 36 + tc * 2 + 1] = pm2_1;
    __syncthreads();
    if (tid < 64) {
        int s  = tid >> 5;
        int uu = tid & 31;
        float sum = 0.f;
        #pragma unroll
        for (int r = 0; r < 16; r++) sum += red[(s * 16 + r) * 36 + uu];
        atomicAdd(((s == 0) ? m1 : m2) + u0 + uu, sum);
    }
}

// K4: memory = alpha*m1 + beta*m2 + mem_partial ; h = o * tanh(memory)
__global__ void k_final(const float* __restrict__ alpha, const float* __restrict__ beta,
                        const float* __restrict__ m1, const float* __restrict__ m2,
                        float* __restrict__ out_h, float* __restrict__ out_mem) {
    int idx = blockIdx.x * 256 + threadIdx.x;   // float4 id, total BB*UU/4
    int b  = idx >> 6;
    int uv = idx & 63;
    float4 mp = ((const float4*)out_mem)[idx];
    float4 ov = ((const float4*)out_h)[idx];
    float al = alpha[b], be = beta[b];
    float4 m1v = ((const float4*)m1)[uv];
    float4 m2v = ((const float4*)m2)[uv];
    float4 mem, h;
    mem.x = fmaf(al, m1v.x, fmaf(be, m2v.x, mp.x)); h.x = ov.x * tanhf(mem.x);
    mem.y = fmaf(al, m1v.y, fmaf(be, m2v.y, mp.y)); h.y = ov.y * tanhf(mem.y);
    mem.z = fmaf(al, m1v.z, fmaf(be, m2v.z, mp.z)); h.z = ov.z * tanhf(mem.z);
    mem.w = fmaf(al, m1v.w, fmaf(be, m2v.w, mp.w)); h.w = ov.w * tanhf(mem.w);
    ((float4*)out_mem)[idx] = mem;
    ((float4*)out_h)[idx]   = h;
}

extern "C" void kernel_launch(void* const* d_in, const int* in_sizes, int n_in,
                              void* d_out, int out_size, void* d_ws, size_t ws_size,
                              hipStream_t stream) {
    const float* inputs   = (const float*)d_in[0];
    const float* h_tm1    = (const float*)d_in[1];
    const float* c_tm1    = (const float*)d_in[2];
    const float* h_tm2    = (const float*)d_in[3];
    const float* c_tm2    = (const float*)d_in[4];
    const int*   neighbors= (const int*)d_in[5];
    const int*   mapping  = (const int*)d_in[6];
    const int*   revmap   = (const int*)d_in[7];
    const int*   timep    = (const int*)d_in[8];
    const float* W        = (const float*)d_in[9];
    const float* Uw       = (const float*)d_in[10];
    const float* Un       = (const float*)d_in[11];
    const float* bias     = (const float*)d_in[12];

    float* ws    = (float*)d_ws;
    float* alpha = ws + WS_ALPHA;
    float* beta  = ws + WS_BETA;
    float* hs1   = ws + WS_HS1;
    float* hs2   = ws + WS_HS2;
    float* m1    = ws + WS_M1;
    float* m2    = ws + WS_M2;
    float* v1    = ws + WS_V1;
    float* v2    = ws + WS_V2;
    float* wc    = ws + WS_WC;

    float* out_h   = (float*)d_out;
    float* out_mem = out_h + BB * UU;

    // zero atomic accumulators (hs1, hs2, m1, m2 are contiguous)
    hipMemsetAsync(hs1, 0, 1024 * sizeof(float), stream);

    k_build_wc<<<640, 256, 0, stream>>>(W, Uw, Un, wc);
    k_colsum<<<256, 256, 0, stream>>>(h_tm1, h_tm2, hs1, hs2);
    k_coef<<<BB / 4, 256, 0, stream>>>(neighbors, mapping, revmap, timep, alpha, beta);
    k_vmat<<<4, 256, 0, stream>>>(Un, hs1, hs2, v1, v2);

    dim3 g3(8, 128);
    k_gemm<<<g3, 256, 0, stream>>>(inputs, h_tm1, c_tm1, c_tm2, wc, bias,
                                   alpha, beta, v1, v2, m1, m2, out_h, out_mem);

    k_final<<<BB * UU / 4 / 256, 256, 0, stream>>>(alpha, beta, m1, m2, out_h, out_mem);
}

// Round 3
// 347.125 us; speedup vs baseline: 1.7155x; 1.7155x over previous
//
#include <hip/hip_runtime.h>
#include <cmath>

// Problem constants
#define BB 16384
#define DD 256
#define UU 256
#define TT 32
#define MM 64

// ws layout (float offsets for f32 region)
#define WS_ALPHA 0
#define WS_BETA  16384
#define WS_HS1   32768
#define WS_HS2   33024
#define WS_M1    33280
#define WS_M2    33536
#define WS_V1    33792
#define WS_V2    34816
#define WS_F32_END 35840   // bytes: 143360
// bf16 region (shorts), starting at byte 143360:
//   A_hi[16 kc][16384 m][32]  = 8388608 shorts (16 MB)
//   A_lo  same                 = 8388608 shorts
//   Bg [8 nb][16 kc][10240]    = 1310720 shorts (2.5 MB; hi 5120 + lo 5120 per tile)
// total ws ~ 36.3 MB

typedef short bf16x8 __attribute__((ext_vector_type(8)));
typedef float f32x4  __attribute__((ext_vector_type(4)));

__device__ __forceinline__ float hsig(float x) {
    return fminf(1.0f, fmaxf(0.0f, fmaf(0.2f, x, 0.5f)));
}
__device__ __forceinline__ short f2bf(float x) {
    unsigned u = __float_as_uint(x);
    unsigned r = (u + 0x7fffu + ((u >> 16) & 1u)) >> 16;
    return (short)r;
}
__device__ __forceinline__ float bf2f(short h) {
    return __uint_as_float(((unsigned)(unsigned short)h) << 16);
}

// ---- conversion: A = [inputs | h_tm1] -> hi/lo bf16, fragment-ordered ----
// layout: A[kc][m][q*8+j] = A_f32[m][kc*32 + q*4 + (j&3) + 16*(j>>2)]
__global__ void k_conv_a(const float* __restrict__ inputs, const float* __restrict__ h1,
                         short* __restrict__ Ahi, short* __restrict__ Alo) {
    int tid = threadIdx.x;
    int b = blockIdx.x;            // 4096 blocks
    int q = tid & 3;
    int m = (b & 255) * 64 + (tid >> 2);
    int kc = b >> 8;
    int k0 = kc * 32 + q * 4;
    const float* src = (k0 < 256) ? (inputs + m * 256 + k0) : (h1 + m * 256 + k0 - 256);
    float4 x0 = *(const float4*)(src);
    float4 x1 = *(const float4*)(src + 16);
    float xs[8] = {x0.x, x0.y, x0.z, x0.w, x1.x, x1.y, x1.z, x1.w};
    bf16x8 hv, lv;
    #pragma unroll
    for (int j = 0; j < 8; j++) {
        short h = f2bf(xs[j]);
        hv[j] = h;
        lv[j] = f2bf(xs[j] - bf2f(h));
    }
    long doff = ((long)kc * 16384 + m) * 32 + q * 8;
    *(bf16x8*)(Ahi + doff) = hv;
    *(bf16x8*)(Alo + doff) = lv;
}

// ---- conversion: B (virtual 512 x 1280, gate-interleaved) -> LDS-image layout ----
// virtual col n = ublk*80 + g*16 + (u&15), u = ublk*16 + (u&15)
// source col: g<4 -> g*256+u ; g==4 (favg) -> 256+u  with row k<256 -> W, else (g<4? U : Un)
// image (per nb,kc, 10240 shorts): hi half then lo half; granule (nl,q) at
// byte ((nl*64+q*16) ^ ((nl&7)<<4)), holding j=0..7 with k = kc*32 + q*4+(j&3)+16*(j>>2)
__global__ void k_conv_b(const float* __restrict__ W, const float* __restrict__ U,
                         const float* __restrict__ Un, short* __restrict__ Bg) {
    int t = blockIdx.x * 256 + threadIdx.x;      // 320 blocks -> 81920 threads
    int q = t & 3;
    int r = t >> 2;
    int nl = r % 160;
    int r2 = r / 160;
    int kc = r2 & 15;
    int nb = r2 >> 4;
    int n = nb * 160 + nl;
    int g = (n >> 4) % 5;
    int u = (n / 80) * 16 + (n & 15);
    int c = (g < 4) ? g * 256 + u : 256 + u;
    bf16x8 hv, lv;
    #pragma unroll
    for (int j = 0; j < 8; j++) {
        int kl = q * 4 + (j & 3) + ((j >> 2) << 4);
        int k = kc * 32 + kl;
        const float* s;
        if (k < 256) s = W + k * 1024 + c;
        else         s = ((g < 4) ? U : Un) + (k - 256) * 1024 + c;
        float x = *s;
        short h = f2bf(x);
        hv[j] = h;
        lv[j] = f2bf(x - bf2f(h));
    }
    int off = (((nl * 64 + q * 16) ^ ((nl & 7) << 4)) >> 1);  // shorts
    short* dst = Bg + (long)(nb * 16 + kc) * 10240 + off;
    *(bf16x8*)dst = hv;
    *(bf16x8*)(dst + 5120) = lv;
}

// ---- hs1/hs2 column sums ----
__global__ void k_colsum(const float* __restrict__ h1, const float* __restrict__ h2,
                         float* __restrict__ hs1, float* __restrict__ hs2) {
    int u = threadIdx.x;
    int r0 = blockIdx.x * 64;
    float s1 = 0.f, s2 = 0.f;
    for (int r = 0; r < 64; r++) {
        s1 += h1[(r0 + r) * UU + u];
        s2 += h2[(r0 + r) * UU + u];
    }
    atomicAdd(hs1 + u, s1);
    atomicAdd(hs2 + u, s2);
}

// ---- per-batch alpha/beta ----
__global__ void k_coef(const int* __restrict__ neighbors, const int* __restrict__ mapping,
                       const int* __restrict__ revmap, const int* __restrict__ timep,
                       float* __restrict__ alpha, float* __restrict__ beta) {
    int lane = threadIdx.x & 63;
    int wid  = threadIdx.x >> 6;
    int b = blockIdx.x * 4 + wid;
    int t = timep[0];
    int p = revmap[b * TT + t];
    int ng = neighbors[(b * TT + p) * MM + lane];
    int mp = mapping[b * MM + lane];
    int cnt = ng;
    int cp  = (mp < t) ? ng : 0;
    #pragma unroll
    for (int off = 32; off > 0; off >>= 1) {
        cnt += __shfl_xor(cnt, off);
        cp  += __shfl_xor(cp, off);
    }
    if (lane == 0) {
        float a = 0.f, be = 0.f;
        if (cnt > 0) {
            float inv = 1.0f / (float)cnt;
            a  = (float)cp * inv;
            be = (float)(cnt - cp) * inv;
        }
        alpha[b] = a;
        beta[b]  = be;
    }
}

// ---- v1 = hs1 @ Un, v2 = hs2 @ Un (atomic k-split, 64 blocks) ----
__global__ void k_vmat(const float* __restrict__ Un, const float* __restrict__ hs1,
                       const float* __restrict__ hs2, float* __restrict__ v1,
                       float* __restrict__ v2) {
    int t = blockIdx.x * 256 + threadIdx.x;   // 16384 threads
    int j = t & 1023;
    int ks = t >> 10;                         // 0..15
    float a1 = 0.f, a2 = 0.f;
    #pragma unroll
    for (int i = 0; i < 16; i++) {
        int k = ks * 16 + i;
        float w = Un[k * 1024 + j];
        a1 = fmaf(hs1[k], w, a1);
        a2 = fmaf(hs2[k], w, a2);
    }
    atomicAdd(v1 + j, a1);
    atomicAdd(v2 + j, a2);
}

// ---- main MFMA GEMM + fused LSTM epilogue ----
// grid (128 m-blocks, 8 nb), 256 threads = 4 waves.
// block tile: M=128 (wave w rows w*32..+31), N_virtual=160 (= 32 units x 5 gates)
// wave tile 32x160: 2 M-frags x 10 N-frags, 3-term split-bf16 accumulation.
#define STAGE_B(KC, BUF) { \
    const char* _s = (const char*)(Bt + (long)(KC) * 10240); \
    char* _d = (char*)(&Bs[BUF][0]); \
    _Pragma("unroll") \
    for (int _c = 0; _c < 5; _c++) { \
        int _u = wv * 5120 + _c * 1024; \
        __builtin_amdgcn_global_load_lds( \
            (const __attribute__((address_space(1))) void*)(_s + _u + lane * 16), \
            (__attribute__((address_space(3))) void*)(_d + _u), 16, 0, 0); \
    } }

__global__ __launch_bounds__(256) void k_gemm_mfma(
    const short* __restrict__ Ahi, const short* __restrict__ Alo,
    const short* __restrict__ Bg,
    const float* __restrict__ c1p, const float* __restrict__ c2p,
    const float* __restrict__ bias,
    const float* __restrict__ alpha, const float* __restrict__ beta,
    const float* __restrict__ v1, const float* __restrict__ v2,
    float* __restrict__ m1, float* __restrict__ m2,
    float* __restrict__ out_h, float* __restrict__ out_mem)
{
    __shared__ short Bs[2][10240];   // 2 x 20 KB (hi 10KB + lo 10KB)

    const int tid = threadIdx.x;
    const int lane = tid & 63;
    const int wv = tid >> 6;
    const int mb = blockIdx.x;
    const int nb = blockIdx.y;
    const int m0 = mb * 128;
    const short* Bt = Bg + (long)nb * 16 * 10240;

    const int uloc = lane & 15;
    const int rgrp = lane >> 4;
    // A fragment base (shorts): [kc][m][32]; row = m0 + wv*32 + mf*16 + uloc, ks-slot = rgrp*8
    const int aoff = (m0 + wv * 32 + uloc) * 32 + rgrp * 8;
    // B LDS read base (bytes) incl XOR swizzle
    const int bbase = ((uloc * 64 + rgrp * 16) ^ ((lane & 7) << 4));

    f32x4 acc[2][10];
    #pragma unroll
    for (int i = 0; i < 2; i++)
        #pragma unroll
        for (int j = 0; j < 10; j++) acc[i][j] = (f32x4){0.f, 0.f, 0.f, 0.f};

    STAGE_B(0, 0);

    for (int kc = 0; kc < 16; kc++) {
        __syncthreads();                         // drains stage(kc) (vmcnt 0) + prev reads
        if (kc + 1 < 16) STAGE_B(kc + 1, (kc + 1) & 1);

        long ab = (long)kc * 524288 + aoff;      // 16384*32 = 524288
        bf16x8 ah0 = *(const bf16x8*)(Ahi + ab);
        bf16x8 ah1 = *(const bf16x8*)(Ahi + ab + 512);
        bf16x8 al0 = *(const bf16x8*)(Alo + ab);
        bf16x8 al1 = *(const bf16x8*)(Alo + ab + 512);

        const char* bp = (const char*)Bs + (kc & 1) * 20480 + bbase;
        #pragma unroll
        for (int nf = 0; nf < 10; nf++) {
            bf16x8 bh = *(const bf16x8*)(bp + nf * 1024);
            bf16x8 bl = *(const bf16x8*)(bp + 10240 + nf * 1024);
            acc[0][nf] = __builtin_amdgcn_mfma_f32_16x16x32_bf16(ah0, bh, acc[0][nf], 0, 0, 0);
            acc[1][nf] = __builtin_amdgcn_mfma_f32_16x16x32_bf16(ah1, bh, acc[1][nf], 0, 0, 0);
            acc[0][nf] = __builtin_amdgcn_mfma_f32_16x16x32_bf16(al0, bh, acc[0][nf], 0, 0, 0);
            acc[1][nf] = __builtin_amdgcn_mfma_f32_16x16x32_bf16(al1, bh, acc[1][nf], 0, 0, 0);
            acc[0][nf] = __builtin_amdgcn_mfma_f32_16x16x32_bf16(ah0, bl, acc[0][nf], 0, 0, 0);
            acc[1][nf] = __builtin_amdgcn_mfma_f32_16x16x32_bf16(ah1, bl, acc[1][nf], 0, 0, 0);
        }
    }

    // ---- fused epilogue; C/D frag: col=lane&15 (unit), row=(lane>>4)*4+reg ----
    float pm1[2] = {0.f, 0.f}, pm2[2] = {0.f, 0.f};
    #pragma unroll
    for (int ub = 0; ub < 2; ub++) {
        int u = nb * 32 + ub * 16 + uloc;
        float bi = bias[u], bfv = bias[256 + u], bc = bias[512 + u], bo = bias[768 + u];
        float v1i = v1[u], v1c = v1[512 + u], v1o = v1[768 + u];
        float v2i = v2[u], v2c = v2[512 + u], v2o = v2[768 + u];
        #pragma unroll
        for (int mf = 0; mf < 2; mf++) {
            int bb = m0 + wv * 32 + mf * 16 + rgrp * 4;
            f32x4 fi = acc[mf][ub * 5 + 0];
            f32x4 ff = acc[mf][ub * 5 + 1];
            f32x4 fc = acc[mf][ub * 5 + 2];
            f32x4 fo = acc[mf][ub * 5 + 3];
            f32x4 fa = acc[mf][ub * 5 + 4];
            #pragma unroll
            for (int r = 0; r < 4; r++) {
                int b = bb + r;
                float al = alpha[b], be = beta[b];
                float c1 = c1p[b * 256 + u];
                float c2 = c2p[b * 256 + u];
                float zi  = fi[r] + bi + al * v1i + be * v2i;
                float zf  = ff[r] + bfv;
                float zc  = fc[r] + bc + al * v1c + be * v2c;
                float zo  = fo[r] + bo + al * v1o + be * v2o;
                float zfa = fa[r] + bfv;
                float ig = hsig(zi), fg = hsig(zf), og = hsig(zo), fav = hsig(zfa);
                float cg = tanhf(zc);
                out_mem[b * 256 + u] = fg * c1 + ig * cg;
                out_h[b * 256 + u]  = og;
                pm1[ub] += fav * c1;
                pm2[ub] += fav * c2;
            }
        }
    }

    // reduce m1/m2 partials: lanes l, l+16, l+32, l+48 share the same unit
    #pragma unroll
    for (int ub = 0; ub < 2; ub++) {
        pm1[ub] += __shfl_xor(pm1[ub], 16); pm1[ub] += __shfl_xor(pm1[ub], 32);
        pm2[ub] += __shfl_xor(pm2[ub], 16); pm2[ub] += __shfl_xor(pm2[ub], 32);
    }
    __syncthreads();
    float* red = (float*)&Bs[0][0];   // [wave][d][ub][16] = 256 floats
    if (rgrp == 0) {
        #pragma unroll
        for (int ub = 0; ub < 2; ub++) {
            red[((wv * 2 + 0) * 2 + ub) * 16 + uloc] = pm1[ub];
            red[((wv * 2 + 1) * 2 + ub) * 16 + uloc] = pm2[ub];
        }
    }
    __syncthreads();
    if (tid < 64) {
        int d = tid >> 5, ub = (tid >> 4) & 1, ui = tid & 15;
        float s = 0.f;
        #pragma unroll
        for (int w = 0; w < 4; w++) s += red[((w * 2 + d) * 2 + ub) * 16 + ui];
        atomicAdd(((d == 0) ? m1 : m2) + nb * 32 + ub * 16 + ui, s);
    }
}

// ---- final: memory = alpha*m1 + beta*m2 + mem_partial ; h = o * tanh(memory) ----
__global__ void k_final(const float* __restrict__ alpha, const float* __restrict__ beta,
                        const float* __restrict__ m1, const float* __restrict__ m2,
                        float* __restrict__ out_h, float* __restrict__ out_mem) {
    int idx = blockIdx.x * 256 + threadIdx.x;   // float4 id
    int b  = idx >> 6;
    int uv = idx & 63;
    float4 mp = ((const float4*)out_mem)[idx];
    float4 ov = ((const float4*)out_h)[idx];
    float al = alpha[b], be = beta[b];
    float4 m1v = ((const float4*)m1)[uv];
    float4 m2v = ((const float4*)m2)[uv];
    float4 mem, h;
    mem.x = fmaf(al, m1v.x, fmaf(be, m2v.x, mp.x)); h.x = ov.x * tanhf(mem.x);
    mem.y = fmaf(al, m1v.y, fmaf(be, m2v.y, mp.y)); h.y = ov.y * tanhf(mem.y);
    mem.z = fmaf(al, m1v.z, fmaf(be, m2v.z, mp.z)); h.z = ov.z * tanhf(mem.z);
    mem.w = fmaf(al, m1v.w, fmaf(be, m2v.w, mp.w)); h.w = ov.w * tanhf(mem.w);
    ((float4*)out_mem)[idx] = mem;
    ((float4*)out_h)[idx]   = h;
}

extern "C" void kernel_launch(void* const* d_in, const int* in_sizes, int n_in,
                              void* d_out, int out_size, void* d_ws, size_t ws_size,
                              hipStream_t stream) {
    const float* inputs   = (const float*)d_in[0];
    const float* h_tm1    = (const float*)d_in[1];
    const float* c_tm1    = (const float*)d_in[2];
    const float* h_tm2    = (const float*)d_in[3];
    const float* c_tm2    = (const float*)d_in[4];
    const int*   neighbors= (const int*)d_in[5];
    const int*   mapping  = (const int*)d_in[6];
    const int*   revmap   = (const int*)d_in[7];
    const int*   timep    = (const int*)d_in[8];
    const float* W        = (const float*)d_in[9];
    const float* Uw       = (const float*)d_in[10];
    const float* Un       = (const float*)d_in[11];
    const float* bias     = (const float*)d_in[12];

    float* ws    = (float*)d_ws;
    float* alpha = ws + WS_ALPHA;
    float* beta  = ws + WS_BETA;
    float* hs1   = ws + WS_HS1;
    float* hs2   = ws + WS_HS2;
    float* m1    = ws + WS_M1;
    float* m2    = ws + WS_M2;
    float* v1    = ws + WS_V1;
    float* v2    = ws + WS_V2;

    short* Ahi = (short*)((char*)d_ws + WS_F32_END * 4);
    short* Alo = Ahi + 8388608;
    short* Bg  = Alo + 8388608;

    float* out_h   = (float*)d_out;
    float* out_mem = out_h + BB * UU;

    // zero atomic accumulators: hs1,hs2,m1,m2,v1,v2 contiguous (3072 floats)
    hipMemsetAsync(hs1, 0, 3072 * sizeof(float), stream);

    k_conv_a<<<4096, 256, 0, stream>>>(inputs, h_tm1, Ahi, Alo);
    k_conv_b<<<320, 256, 0, stream>>>(W, Uw, Un, Bg);
    k_colsum<<<256, 256, 0, stream>>>(h_tm1, h_tm2, hs1, hs2);
    k_coef<<<BB / 4, 256, 0, stream>>>(neighbors, mapping, revmap, timep, alpha, beta);
    k_vmat<<<64, 256, 0, stream>>>(Un, hs1, hs2, v1, v2);

    dim3 g3(128, 8);
    k_gemm_mfma<<<g3, 256, 0, stream>>>(Ahi, Alo, Bg, c_tm1, c_tm2, bias,
                                        alpha, beta, v1, v2, m1, m2, out_h, out_mem);

    k_final<<<BB * UU / 4 / 256, 256, 0, stream>>>(alpha, beta, m1, m2, out_h, out_mem);
}